// Round 5
// baseline (368.955 us; speedup 1.0000x reference)
//
#include <hip/hip_runtime.h>

#define B_ 8
#define T_ 2048
#define H_ 256
#define BR 32
#define BC 64
#define KSTR 264           // K LDS row stride (elems): 132 dw == 4 mod 32
#define VSTR 72            // V LDS row stride: 36 dw == 4 mod 32
#define PSTR 72
#define SCALE2 0.0901684403f     // (1/16) * log2(e)
#define SLOPE2 0.00563552752f    // 2^-8 * log2(e)

typedef __attribute__((ext_vector_type(8))) short bf16x8;
typedef __attribute__((ext_vector_type(4))) float f32x4;

#define MFMA16(a, b, c) __builtin_amdgcn_mfma_f32_16x16x32_bf16((a), (b), (c), 0, 0, 0)

__device__ __forceinline__ ushort f2bf(float f) {
  unsigned u = __float_as_uint(f);
  u += 0x7FFFu + ((u >> 16) & 1u);   // RNE; finite inputs
  return (ushort)(u >> 16);
}

// ---- fused prologue: blocks [0,256) RoPE(q,k)->bf16; [256,1280) v transpose ----
__global__ void prep_kernel(const float* __restrict__ q, const float* __restrict__ k,
                            const float* __restrict__ v,
                            ushort* __restrict__ qe, ushort* __restrict__ ke,
                            ushort* __restrict__ vt) {
  __shared__ ushort tile[64][72];
  const int bid = blockIdx.x;
  const int tid = threadIdx.x;
  if (bid < 256) {
    // RoPE: 8 t-rows per block; thread covers j..j+3 (paired with j+128..j+131),
    // sincos computed once and reused across the batch loop.
    int t = bid * 8 + (tid >> 5);
    int j = (tid & 31) * 4;
    float cs[4], sn[4];
#pragma unroll
    for (int i = 0; i < 4; ++i) {
      // revolutions = t * invfreq / (2pi); v_sin/v_cos take revolutions
      float rv = (float)t * exp2f((float)(j + i) * -0.103810252959f) * 0.15915494309f;
      float fr = rv - floorf(rv);
      sn[i] = __builtin_amdgcn_sinf(fr);
      cs[i] = __builtin_amdgcn_cosf(fr);
    }
    for (int b = 0; b < B_; ++b) {
      size_t base = ((size_t)(b * T_ + t)) * H_ + j;
      float4 lo = *(const float4*)(q + base);
      float4 hi = *(const float4*)(q + base + 128);
      ushort4 olo, ohi;
      olo.x = f2bf(lo.x * cs[0] - hi.x * sn[0]); ohi.x = f2bf(hi.x * cs[0] + lo.x * sn[0]);
      olo.y = f2bf(lo.y * cs[1] - hi.y * sn[1]); ohi.y = f2bf(hi.y * cs[1] + lo.y * sn[1]);
      olo.z = f2bf(lo.z * cs[2] - hi.z * sn[2]); ohi.z = f2bf(hi.z * cs[2] + lo.z * sn[2]);
      olo.w = f2bf(lo.w * cs[3] - hi.w * sn[3]); ohi.w = f2bf(hi.w * cs[3] + lo.w * sn[3]);
      *(ushort4*)(qe + base) = olo; *(ushort4*)(qe + base + 128) = ohi;
      lo = *(const float4*)(k + base);
      hi = *(const float4*)(k + base + 128);
      olo.x = f2bf(lo.x * cs[0] - hi.x * sn[0]); ohi.x = f2bf(hi.x * cs[0] + lo.x * sn[0]);
      olo.y = f2bf(lo.y * cs[1] - hi.y * sn[1]); ohi.y = f2bf(hi.y * cs[1] + lo.y * sn[1]);
      olo.z = f2bf(lo.z * cs[2] - hi.z * sn[2]); ohi.z = f2bf(hi.z * cs[2] + lo.z * sn[2]);
      olo.w = f2bf(lo.w * cs[3] - hi.w * sn[3]); ohi.w = f2bf(hi.w * cs[3] + lo.w * sn[3]);
      *(ushort4*)(ke + base) = olo; *(ushort4*)(ke + base + 128) = ohi;
    }
  } else {
    // V transpose: v[B,T,H] fp32 -> vt[B,H,T] bf16, 64x64 tiles, XOR-8 swizzle
    int bid2 = bid - 256;
    int b = bid2 >> 7, rem = bid2 & 127;
    int h0 = (rem >> 5) * 64, t0 = (rem & 31) * 64;
    int c4 = tid & 15, r0 = tid >> 4;
#pragma unroll
    for (int p = 0; p < 4; ++p) {
      int row = r0 + p * 16;
      const float4 f = *(const float4*)(v + ((size_t)(b * T_ + t0 + row)) * H_ + h0 + c4 * 4);
      ushort4 u;
      u.x = f2bf(f.x); u.y = f2bf(f.y); u.z = f2bf(f.z); u.w = f2bf(f.w);
      *(ushort4*)&tile[row][(c4 * 4) ^ (8 * ((row >> 3) & 7))] = u;
    }
    __syncthreads();
#pragma unroll
    for (int p = 0; p < 2; ++p) {
      int c = tid + p * 256;
      int h = c >> 3, tc = (c & 7) * 8;
      int xo = 8 * (c & 7);
      ushort4 u0, u1;
      u0.x = tile[tc + 0][h ^ xo]; u0.y = tile[tc + 1][h ^ xo];
      u0.z = tile[tc + 2][h ^ xo]; u0.w = tile[tc + 3][h ^ xo];
      u1.x = tile[tc + 4][h ^ xo]; u1.y = tile[tc + 5][h ^ xo];
      u1.z = tile[tc + 6][h ^ xo]; u1.w = tile[tc + 7][h ^ xo];
      ushort* dst = vt + ((size_t)(b * H_ + h0 + h)) * T_ + t0 + tc;
      *(ushort4*)dst = u0;
      *(ushort4*)(dst + 4) = u1;
    }
  }
}

// ---- Flash attention, no-max softmax, register-prefetch pipelined K/V staging ----
// 4 waves; wave w: S cols [16w,16w+16), O h-slice [64w,64w+64). grid (b, q-block)
// so linear block id % 8 == b -> same-batch blocks share an XCD L2 (K/V fit 4MB).
__global__ __launch_bounds__(256, 2)
void attn_kernel(const ushort* __restrict__ qe, const ushort* __restrict__ ke,
                 const ushort* __restrict__ vT, float* __restrict__ out) {
  __shared__ ushort Ksh[BC * KSTR];     // 33792 B
  __shared__ ushort Vsh[4][64 * VSTR];  // 36864 B
  __shared__ ushort Psh[BR * PSTR];     // 4608 B  -> 75264 B, 2 blocks/CU

  const int tid = threadIdx.x;
  const int w = tid >> 6, lane = tid & 63, quad = lane >> 4, l16 = lane & 15;
  const int b = blockIdx.x;
  const int q0 = blockIdx.y * BR;

  // Q A-fragments in registers, loaded once
  bf16x8 aq[2][8];
  const ushort* qbase = qe + (size_t)(b * T_ + q0) * H_;
#pragma unroll
  for (int mt = 0; mt < 2; ++mt)
#pragma unroll
    for (int ks = 0; ks < 8; ++ks)
      aq[mt][ks] = *(const bf16x8*)(qbase + (size_t)(mt * 16 + l16) * H_ + ks * 32 + quad * 8);

  const f32x4 fzero = {0.f, 0.f, 0.f, 0.f};
  f32x4 O[2][4], lac[2];
#pragma unroll
  for (int mt = 0; mt < 2; ++mt) {
    lac[mt] = fzero;
#pragma unroll
    for (int ht = 0; ht < 4; ++ht) O[mt][ht] = fzero;
  }
  bf16x8 vones;
#pragma unroll
  for (int i = 0; i < 8; ++i) vones[i] = (short)0x3F80;   // bf16 1.0

  // staging addresses
  const ushort* ksrc = ke + (size_t)(b * T_ + (tid >> 5)) * H_ + (tid & 31) * 8;
  const int kdst = (tid >> 5) * KSTR + (tid & 31) * 8;
  const ushort* vsrc = vT + (size_t)(b * H_ + w * 64 + (lane >> 3)) * T_ + (lane & 7) * 8;
  ushort* vshw = &Vsh[w][0];
  const int vdst = (lane >> 3) * VSTR + (lane & 7) * 8;

  // prefetch tile 0 into registers
  uint4 kb[8], vb[8];
#pragma unroll
  for (int i = 0; i < 8; ++i) {
    kb[i] = *(const uint4*)(ksrc + (size_t)i * (8 * H_));
    vb[i] = *(const uint4*)(vsrc + (size_t)i * (8 * T_));
  }

  const float ar0 = SLOPE2 * (float)(q0 + quad * 4);

  for (int it = 0; it < T_ / BC; ++it) {     // 32 iters
    __syncthreads();   // prev iter's LDS readers done
#pragma unroll
    for (int i = 0; i < 8; ++i) {
      *(uint4*)&Ksh[kdst + i * (8 * KSTR)] = kb[i];
      *(uint4*)&vshw[vdst + i * (8 * VSTR)] = vb[i];
    }
    __syncthreads();   // tiles ready

    // issue next tile's global loads NOW — latency hides behind compute
    if (it != T_ / BC - 1) {
      const ushort* ks = ksrc + (size_t)(it + 1) * BC * H_;
      const ushort* vs = vsrc + (size_t)(it + 1) * BC;
#pragma unroll
      for (int i = 0; i < 8; ++i) {
        kb[i] = *(const uint4*)(ks + (size_t)i * (8 * H_));
        vb[i] = *(const uint4*)(vs + (size_t)i * (8 * T_));
      }
    }

    // QK^T: S[0:32][16w:16w+16]
    f32x4 s0 = fzero, s1 = fzero;
    const int krow = (w * 16 + l16) * KSTR + quad * 8;
#pragma unroll
    for (int kk = 0; kk < 8; ++kk) {
      bf16x8 bk = *(const bf16x8*)&Ksh[krow + kk * 32];
      s0 = MFMA16(aq[0][kk], bk, s0);
      s1 = MFMA16(aq[1][kk], bk, s1);
    }
    // p = exp2(s*SCALE2 + SLOPE2*(col - row)) -> bf16 Psh
    const float ac = SLOPE2 * (float)(it * BC + w * 16 + l16);
#pragma unroll
    for (int r = 0; r < 4; ++r) {
      float a0 = ac - ar0 - SLOPE2 * (float)r;
      float p0 = __builtin_amdgcn_exp2f(fmaf(s0[r], SCALE2, a0));
      float p1 = __builtin_amdgcn_exp2f(fmaf(s1[r], SCALE2, a0 - SLOPE2 * 16.0f));
      Psh[(quad * 4 + r) * PSTR + w * 16 + l16] = f2bf(p0);
      Psh[(16 + quad * 4 + r) * PSTR + w * 16 + l16] = f2bf(p1);
    }
    __syncthreads();   // P complete

    // PV + rowsum(P) via ones-MFMA
#pragma unroll
    for (int s2 = 0; s2 < 2; ++s2) {
      bf16x8 a0 = *(const bf16x8*)&Psh[l16 * PSTR + s2 * 32 + quad * 8];
      bf16x8 a1 = *(const bf16x8*)&Psh[(16 + l16) * PSTR + s2 * 32 + quad * 8];
      lac[0] = MFMA16(a0, vones, lac[0]);
      lac[1] = MFMA16(a1, vones, lac[1]);
#pragma unroll
      for (int ht = 0; ht < 4; ++ht) {
        bf16x8 bv = *(const bf16x8*)&vshw[(ht * 16 + l16) * VSTR + s2 * 32 + quad * 8];
        O[0][ht] = MFMA16(a0, bv, O[0][ht]);
        O[1][ht] = MFMA16(a1, bv, O[1][ht]);
      }
    }
  }

  float* obase = out + (size_t)(b * T_ + q0) * H_ + w * 64;
#pragma unroll
  for (int mt = 0; mt < 2; ++mt)
#pragma unroll
    for (int r = 0; r < 4; ++r) {
      int row = mt * 16 + quad * 4 + r;
      float inv = 1.0f / lac[mt][r];
#pragma unroll
      for (int ht = 0; ht < 4; ++ht)
        obase[(size_t)row * H_ + ht * 16 + l16] = O[mt][ht][r] * inv;
    }
}

extern "C" void kernel_launch(void* const* d_in, const int* in_sizes, int n_in,
                              void* d_out, int out_size, void* d_ws, size_t ws_size,
                              hipStream_t stream) {
  const float* q = (const float*)d_in[0];
  const float* k = (const float*)d_in[1];
  const float* v = (const float*)d_in[2];
  float* out = (float*)d_out;

  const size_t elems = (size_t)B_ * T_ * H_;
  ushort* qe = (ushort*)d_ws;
  ushort* ke = qe + elems;
  ushort* vt = ke + elems;

  prep_kernel<<<dim3(1280), 256, 0, stream>>>(q, k, v, qe, ke, vt);
  attn_kernel<<<dim3(B_, T_ / BR), 256, 0, stream>>>(qe, ke, vt, out);
}

// Round 6
// 209.936 us; speedup vs baseline: 1.7575x; 1.7575x over previous
//
#include <hip/hip_runtime.h>

#define B_ 8
#define T_ 2048
#define H_ 256
#define BR 32
#define BC 64
#define PSTR 72
#define SCALE2 0.0901684403f     // (1/16) * log2(e)
#define SLOPE2 0.00563552752f    // 2^-8 * log2(e)

typedef __attribute__((ext_vector_type(8))) short bf16x8;
typedef __attribute__((ext_vector_type(4))) float f32x4;

#define MFMA16(a, b, c) __builtin_amdgcn_mfma_f32_16x16x32_bf16((a), (b), (c), 0, 0, 0)

__device__ __forceinline__ ushort f2bf(float f) {
  unsigned u = __float_as_uint(f);
  u += 0x7FFFu + ((u >> 16) & 1u);   // RNE; finite inputs
  return (ushort)(u >> 16);
}

// lgkm-only barrier: orders LDS ops across the workgroup WITHOUT draining
// in-flight global loads (avoids the vmcnt(0)-before-s_barrier stall).
__device__ __forceinline__ void lds_barrier() {
  __builtin_amdgcn_sched_barrier(0);
  __builtin_amdgcn_s_waitcnt(0xC07F);   // vmcnt=63(no-wait), exp=7, lgkmcnt=0
  __builtin_amdgcn_s_barrier();
  __builtin_amdgcn_sched_barrier(0);
}

// ---- prologue: blocks [0,4096) RoPE(q,k)->bf16 elementwise; [4096,5120) v transpose ----
__global__ void prep_kernel(const float* __restrict__ q, const float* __restrict__ k,
                            const float* __restrict__ v,
                            ushort* __restrict__ qe, ushort* __restrict__ ke,
                            ushort* __restrict__ vt) {
  __shared__ ushort tile[64][72];
  const int bid = blockIdx.x;
  const int tid = threadIdx.x;
  if (bid < 4096) {
    int idx = bid * 256 + tid;          // over B*T*64 (j-pairs of 2)
    int jp = idx & 63, bt = idx >> 6;
    int t = bt & (T_ - 1);
    int j = jp * 2;
    float rv0 = (float)t * exp2f((float)j * -0.103810252959f) * 0.15915494309f;
    float rv1 = (float)t * exp2f((float)(j + 1) * -0.103810252959f) * 0.15915494309f;
    float fr0 = rv0 - floorf(rv0), fr1 = rv1 - floorf(rv1);
    float sn0 = __builtin_amdgcn_sinf(fr0), cs0 = __builtin_amdgcn_cosf(fr0);
    float sn1 = __builtin_amdgcn_sinf(fr1), cs1 = __builtin_amdgcn_cosf(fr1);
    size_t base = (size_t)bt * H_ + j;
    float2 a = *(const float2*)(q + base);
    float2 c = *(const float2*)(q + base + 128);
    ushort2 lo, hi;
    lo.x = f2bf(a.x * cs0 - c.x * sn0); lo.y = f2bf(a.y * cs1 - c.y * sn1);
    hi.x = f2bf(c.x * cs0 + a.x * sn0); hi.y = f2bf(c.y * cs1 + a.y * sn1);
    *(ushort2*)(qe + base) = lo; *(ushort2*)(qe + base + 128) = hi;
    a = *(const float2*)(k + base);
    c = *(const float2*)(k + base + 128);
    lo.x = f2bf(a.x * cs0 - c.x * sn0); lo.y = f2bf(a.y * cs1 - c.y * sn1);
    hi.x = f2bf(c.x * cs0 + a.x * sn0); hi.y = f2bf(c.y * cs1 + a.y * sn1);
    *(ushort2*)(ke + base) = lo; *(ushort2*)(ke + base + 128) = hi;
  } else {
    // V transpose: v[B,T,H] fp32 -> vt[B,H,T] bf16, 64x64 tiles, XOR-8 swizzle
    int bid2 = bid - 4096;
    int b = bid2 >> 7, rem = bid2 & 127;
    int h0 = (rem >> 5) * 64, t0 = (rem & 31) * 64;
    int c4 = tid & 15, r0 = tid >> 4;
#pragma unroll
    for (int p = 0; p < 4; ++p) {
      int row = r0 + p * 16;
      const float4 f = *(const float4*)(v + ((size_t)(b * T_ + t0 + row)) * H_ + h0 + c4 * 4);
      ushort4 u;
      u.x = f2bf(f.x); u.y = f2bf(f.y); u.z = f2bf(f.z); u.w = f2bf(f.w);
      *(ushort4*)&tile[row][(c4 * 4) ^ (8 * ((row >> 3) & 7))] = u;
    }
    __syncthreads();
#pragma unroll
    for (int p = 0; p < 2; ++p) {
      int c = tid + p * 256;
      int h = c >> 3, tc = (c & 7) * 8;
      int xo = 8 * (c & 7);
      ushort4 u0, u1;
      u0.x = tile[tc + 0][h ^ xo]; u0.y = tile[tc + 1][h ^ xo];
      u0.z = tile[tc + 2][h ^ xo]; u0.w = tile[tc + 3][h ^ xo];
      u1.x = tile[tc + 4][h ^ xo]; u1.y = tile[tc + 5][h ^ xo];
      u1.z = tile[tc + 6][h ^ xo]; u1.w = tile[tc + 7][h ^ xo];
      ushort* dst = vt + ((size_t)(b * H_ + h0 + h)) * T_ + t0 + tc;
      *(ushort4*)dst = u0;
      *(ushort4*)(dst + 4) = u1;
    }
  }
}

// ---- Flash attention: no-max softmax; K/V loaded straight into MFMA fragments ----
// Wave w is self-sufficient for K (rows [16w,16w+16)) and V (h-slice [64w,64w+64));
// only the P transpose round-trips through LDS (lgkm-only barriers).
__global__ __launch_bounds__(256, 2)
void attn_kernel(const ushort* __restrict__ qe, const ushort* __restrict__ ke,
                 const ushort* __restrict__ vT, float* __restrict__ out) {
  __shared__ ushort Psh[BR * PSTR];     // 4608 B — only LDS in the kernel

  const int tid = threadIdx.x;
  const int w = tid >> 6, lane = tid & 63, quad = lane >> 4, l16 = lane & 15;
  const int b = blockIdx.x;             // linear%8 == b -> XCD affinity per batch
  const int q0 = blockIdx.y * BR;

  // Q A-fragments, loaded once
  bf16x8 aq[2][8];
  const ushort* qbase = qe + (size_t)(b * T_ + q0) * H_;
#pragma unroll
  for (int mt = 0; mt < 2; ++mt)
#pragma unroll
    for (int ks = 0; ks < 8; ++ks)
      aq[mt][ks] = *(const bf16x8*)(qbase + (size_t)(mt * 16 + l16) * H_ + ks * 32 + quad * 8);

  const f32x4 fzero = {0.f, 0.f, 0.f, 0.f};
  f32x4 O[2][4], lac[2];
#pragma unroll
  for (int mt = 0; mt < 2; ++mt) {
    lac[mt] = fzero;
#pragma unroll
    for (int ht = 0; ht < 4; ++ht) O[mt][ht] = fzero;
  }
  bf16x8 vones;
#pragma unroll
  for (int i = 0; i < 8; ++i) vones[i] = (short)0x3F80;   // bf16 1.0

  // per-lane fragment gather bases
  const ushort* kgbase = ke + ((size_t)(b * T_ + 16 * w + l16)) * H_ + quad * 8;
  const ushort* vgbase = vT + ((size_t)(b * H_ + 64 * w + l16)) * T_ + quad * 8;

  // preload K fragments for tile 0
  bf16x8 kc[8];
#pragma unroll
  for (int kk = 0; kk < 8; ++kk)
    kc[kk] = *(const bf16x8*)(kgbase + kk * 32);

  const float ar0 = SLOPE2 * (float)(q0 + quad * 4);

  for (int it = 0; it < T_ / BC; ++it) {     // 32 iters
    // V fragments for THIS iter — in flight during QK + exp
    bf16x8 vc[8];
    {
      const ushort* vg = vgbase + (size_t)it * BC;
#pragma unroll
      for (int ht = 0; ht < 4; ++ht)
#pragma unroll
        for (int s2 = 0; s2 < 2; ++s2)
          vc[ht * 2 + s2] = *(const bf16x8*)(vg + (size_t)(ht * 16) * T_ + s2 * 32);
    }

    // QK^T: S[0:32][16w:16w+16]
    f32x4 s0 = fzero, s1 = fzero;
#pragma unroll
    for (int kk = 0; kk < 8; ++kk) {
      s0 = MFMA16(aq[0][kk], kc[kk], s0);
      s1 = MFMA16(aq[1][kk], kc[kk], s1);
    }

    // reload kc with NEXT tile (last use was above; in flight across barriers+PV)
    {
      int itn = (it < T_ / BC - 1) ? it + 1 : it;
      const ushort* kg = kgbase + (size_t)itn * BC * H_;
#pragma unroll
      for (int kk = 0; kk < 8; ++kk)
        kc[kk] = *(const bf16x8*)(kg + kk * 32);
    }

    // p = exp2(s*SCALE2 + SLOPE2*(col-row))
    const float ac = SLOPE2 * (float)(it * BC + 16 * w + l16);
    float p0[4], p1[4];
#pragma unroll
    for (int r = 0; r < 4; ++r) {
      float a0 = ac - ar0 - SLOPE2 * (float)r;
      p0[r] = __builtin_amdgcn_exp2f(fmaf(s0[r], SCALE2, a0));
      p1[r] = __builtin_amdgcn_exp2f(fmaf(s1[r], SCALE2, a0 - SLOPE2 * 16.0f));
    }

    lds_barrier();   // prev iter's Psh readers drained (lgkm only)
#pragma unroll
    for (int r = 0; r < 4; ++r) {
      Psh[(quad * 4 + r) * PSTR + 16 * w + l16] = f2bf(p0[r]);
      Psh[(16 + quad * 4 + r) * PSTR + 16 * w + l16] = f2bf(p1[r]);
    }
    lds_barrier();   // Psh published

    // PV + rowsum(P) via ones-MFMA
#pragma unroll
    for (int s2 = 0; s2 < 2; ++s2) {
      bf16x8 a0 = *(const bf16x8*)&Psh[l16 * PSTR + s2 * 32 + quad * 8];
      bf16x8 a1 = *(const bf16x8*)&Psh[(16 + l16) * PSTR + s2 * 32 + quad * 8];
      lac[0] = MFMA16(a0, vones, lac[0]);
      lac[1] = MFMA16(a1, vones, lac[1]);
#pragma unroll
      for (int ht = 0; ht < 4; ++ht) {
        O[0][ht] = MFMA16(a0, vc[ht * 2 + s2], O[0][ht]);
        O[1][ht] = MFMA16(a1, vc[ht * 2 + s2], O[1][ht]);
      }
    }
  }

  float* obase = out + (size_t)(b * T_ + q0) * H_ + w * 64;
#pragma unroll
  for (int mt = 0; mt < 2; ++mt)
#pragma unroll
    for (int r = 0; r < 4; ++r) {
      int row = mt * 16 + quad * 4 + r;
      float inv = 1.0f / lac[mt][r];
#pragma unroll
      for (int ht = 0; ht < 4; ++ht)
        obase[(size_t)row * H_ + ht * 16 + l16] = O[mt][ht][r] * inv;
    }
}

extern "C" void kernel_launch(void* const* d_in, const int* in_sizes, int n_in,
                              void* d_out, int out_size, void* d_ws, size_t ws_size,
                              hipStream_t stream) {
  const float* q = (const float*)d_in[0];
  const float* k = (const float*)d_in[1];
  const float* v = (const float*)d_in[2];
  float* out = (float*)d_out;

  const size_t elems = (size_t)B_ * T_ * H_;
  ushort* qe = (ushort*)d_ws;
  ushort* ke = qe + elems;
  ushort* vt = ke + elems;

  prep_kernel<<<dim3(5120), 256, 0, stream>>>(q, k, v, qe, ke, vt);
  attn_kernel<<<dim3(B_, T_ / BR), 256, 0, stream>>>(qe, ke, vt, out);
}

// Round 7
// 206.334 us; speedup vs baseline: 1.7881x; 1.0175x over previous
//
#include <hip/hip_runtime.h>

#define B_ 8
#define T_ 2048
#define H_ 256
#define PSTR 40                  // P LDS row stride (elems): 20 dw -> 2-way max on b128
#define SCALE2 0.0901684403f     // (1/16) * log2(e)
#define SLOPE2 0.00563552752f    // 2^-8 * log2(e)

typedef __attribute__((ext_vector_type(8))) short bf16x8;
typedef __attribute__((ext_vector_type(4))) float f32x4;

#define MFMA16(a, b, c) __builtin_amdgcn_mfma_f32_16x16x32_bf16((a), (b), (c), 0, 0, 0)

__device__ __forceinline__ ushort f2bf(float f) {
  unsigned u = __float_as_uint(f);
  u += 0x7FFFu + ((u >> 16) & 1u);   // RNE; finite inputs
  return (ushort)(u >> 16);
}

// async 16B/lane global->LDS DMA (contiguous: LDS = uniform base + lane*16)
__device__ __forceinline__ void gl_lds16(const ushort* g, ushort* l) {
  __builtin_amdgcn_global_load_lds(
      (const __attribute__((address_space(1))) unsigned int*)g,
      (__attribute__((address_space(3))) unsigned int*)l, 16, 0, 0);
}

// ---- prologue: blocks [0,4096) RoPE(k)->bf16 blocked ktile; [4096,5120) v transpose ----
// ktile layout: [b][it=t/32][d8=d/8][kv=t%32][8]   (16KB contiguous per (b,it) tile)
// vtile layout: [b][it][q4=(t%32)/8][h][8]
__global__ void prep_kernel(const float* __restrict__ k, const float* __restrict__ v,
                            ushort* __restrict__ kt, ushort* __restrict__ vt) {
  __shared__ ushort tile[64][72];
  const int bid = blockIdx.x;
  const int tid = threadIdx.x;
  if (bid < 4096) {
    int idx = bid * 256 + tid;          // over B*T*64 (j-pairs)
    int jp = idx & 63, bt = idx >> 6;
    int t = bt & (T_ - 1);
    int b = bt >> 11;
    int j = jp * 2;
    float rv0 = (float)t * exp2f((float)j * -0.103810252959f) * 0.15915494309f;
    float rv1 = (float)t * exp2f((float)(j + 1) * -0.103810252959f) * 0.15915494309f;
    float fr0 = rv0 - floorf(rv0), fr1 = rv1 - floorf(rv1);
    float sn0 = __builtin_amdgcn_sinf(fr0), cs0 = __builtin_amdgcn_cosf(fr0);
    float sn1 = __builtin_amdgcn_sinf(fr1), cs1 = __builtin_amdgcn_cosf(fr1);
    size_t base = (size_t)bt * H_ + j;
    float2 a = *(const float2*)(k + base);
    float2 c = *(const float2*)(k + base + 128);
    ushort2 lo, hi;
    lo.x = f2bf(a.x * cs0 - c.x * sn0); lo.y = f2bf(a.y * cs1 - c.y * sn1);
    hi.x = f2bf(c.x * cs0 + a.x * sn0); hi.y = f2bf(c.y * cs1 + a.y * sn1);
    size_t kdst = (((size_t)(b * 64 + (t >> 5)) * 32 + (j >> 3)) * 32 + (t & 31)) * 8 + (j & 7);
    *(ushort2*)(kt + kdst) = lo;
    *(ushort2*)(kt + kdst + 4096) = hi;   // d8 + 16
  } else {
    // V transpose into blocked vtile, 64x64 tiles, XOR-8 swizzle in LDS
    int bid2 = bid - 4096;
    int b = bid2 >> 7, rem = bid2 & 127;
    int h0 = (rem >> 5) * 64, t0 = (rem & 31) * 64;
    int c4 = tid & 15, r0 = tid >> 4;
#pragma unroll
    for (int p = 0; p < 4; ++p) {
      int row = r0 + p * 16;
      const float4 f = *(const float4*)(v + ((size_t)(b * T_ + t0 + row)) * H_ + h0 + c4 * 4);
      ushort4 u;
      u.x = f2bf(f.x); u.y = f2bf(f.y); u.z = f2bf(f.z); u.w = f2bf(f.w);
      *(ushort4*)&tile[row][(c4 * 4) ^ (8 * ((row >> 3) & 7))] = u;
    }
    __syncthreads();
#pragma unroll
    for (int p = 0; p < 2; ++p) {
      int c = tid + p * 256;
      int h = c >> 3, tc = (c & 7) * 8;
      int xo = 8 * (c & 7);
      ushort4 u0, u1;
      u0.x = tile[tc + 0][h ^ xo]; u0.y = tile[tc + 1][h ^ xo];
      u0.z = tile[tc + 2][h ^ xo]; u0.w = tile[tc + 3][h ^ xo];
      u1.x = tile[tc + 4][h ^ xo]; u1.y = tile[tc + 5][h ^ xo];
      u1.z = tile[tc + 6][h ^ xo]; u1.w = tile[tc + 7][h ^ xo];
      int tg = t0 + tc;
      size_t dst = (((size_t)(b * 64 + (tg >> 5)) * 4 + ((tg >> 3) & 3)) * 256 + (h0 + h)) * 8;
      *(ushort4*)(vt + dst) = u0;
      *(ushort4*)(vt + dst + 4) = u1;
    }
  }
}

// ---- Flash attention: 2 waves x 32 rows; K ping-pong + V single via global_load_lds;
// P wave-private; no-max softmax; fully pipelined barriers (no young vmcnt drains).
__global__ __launch_bounds__(128, 1)
void attn_kernel(const float* __restrict__ q, const ushort* __restrict__ kt,
                 const ushort* __restrict__ vt, float* __restrict__ out) {
  __shared__ ushort Ksh[2][8192];       // [buf][d8][kv32][8]  32 KB
  __shared__ ushort Vsh[8192];          // [q4][h256][8]       16 KB
  __shared__ ushort Psh[2][32 * PSTR];  // per-wave P          5 KB

  const int tid = threadIdx.x;
  const int w = tid >> 6, lane = tid & 63, quad = lane >> 4, l16 = lane & 15;
  const int b = blockIdx.x;             // linear%8==b -> XCD affinity
  const int q0 = blockIdx.y * 64;

  // ---- in-register RoPE of this wave's 32 Q rows into A-frags ----
  bf16x8 aq[2][8];
  {
    const float* qb = q + ((size_t)(b * T_) + q0 + w * 32) * H_;
#pragma unroll
    for (int mt = 0; mt < 2; ++mt) {
      int t = q0 + w * 32 + mt * 16 + l16;
      float qv[8][8];
#pragma unroll
      for (int ks = 0; ks < 8; ++ks) {
        float4 x0 = *(const float4*)(qb + (size_t)(mt * 16 + l16) * H_ + ks * 32 + quad * 8);
        float4 x1 = *(const float4*)(qb + (size_t)(mt * 16 + l16) * H_ + ks * 32 + quad * 8 + 4);
        qv[ks][0] = x0.x; qv[ks][1] = x0.y; qv[ks][2] = x0.z; qv[ks][3] = x0.w;
        qv[ks][4] = x1.x; qv[ks][5] = x1.y; qv[ks][6] = x1.z; qv[ks][7] = x1.w;
      }
#pragma unroll
      for (int ks = 0; ks < 4; ++ks)
#pragma unroll
        for (int e = 0; e < 8; ++e) {
          int d = ks * 32 + quad * 8 + e;
          float rv = (float)t * exp2f((float)d * -0.103810252959f) * 0.15915494309f;
          float fr = rv - floorf(rv);
          float sn = __builtin_amdgcn_sinf(fr), cs = __builtin_amdgcn_cosf(fr);
          aq[mt][ks][e]     = (short)f2bf(qv[ks][e] * cs - qv[ks + 4][e] * sn);
          aq[mt][ks + 4][e] = (short)f2bf(qv[ks + 4][e] * cs + qv[ks][e] * sn);
        }
    }
  }

  const f32x4 fzero = {0.f, 0.f, 0.f, 0.f};
  f32x4 O[2][16], lac[2];
#pragma unroll
  for (int mt = 0; mt < 2; ++mt) {
    lac[mt] = fzero;
#pragma unroll
    for (int ht = 0; ht < 16; ++ht) O[mt][ht] = fzero;
  }
  bf16x8 vones;
#pragma unroll
  for (int i = 0; i < 8; ++i) vones[i] = (short)0x3F80;

  const ushort* ktb = kt + (size_t)(b * 64) * 8192;
  const ushort* vtb = vt + (size_t)(b * 64) * 8192;
  const int stoff = w * 4096 + lane * 8;   // elems: wave-half + lane*16B

  // preload K tile 0 into Ksh[0]
#pragma unroll
  for (int i = 0; i < 8; ++i)
    gl_lds16(ktb + stoff + i * 512, &Ksh[0][stoff + i * 512]);
  __builtin_amdgcn_sched_barrier(0);
  __builtin_amdgcn_s_waitcnt(0x0070);   // vmcnt(0) lgkm(0)
  __builtin_amdgcn_s_barrier();
  __builtin_amdgcn_sched_barrier(0);

  const float arb = SLOPE2 * (float)(q0 + w * 32 + quad * 4);

  for (int it = 0; it < 64; ++it) {
    const int p = it & 1;
    // issue V(it) then K(it+1) — V retires first (in-order vmcnt)
    {
      const ushort* vg = vtb + (size_t)it * 8192;
#pragma unroll
      for (int i = 0; i < 8; ++i)
        gl_lds16(vg + stoff + i * 512, &Vsh[stoff + i * 512]);
      const int itn = (it < 63) ? it + 1 : 63;
      const ushort* kg = ktb + (size_t)itn * 8192;
#pragma unroll
      for (int i = 0; i < 8; ++i)
        gl_lds16(kg + stoff + i * 512, &Ksh[1 - p][stoff + i * 512]);
    }
    __builtin_amdgcn_sched_barrier(0);

    // QK on Ksh[p]: S = [2 m-tiles][2 n-tiles]
    f32x4 s[2][2] = {{fzero, fzero}, {fzero, fzero}};
#pragma unroll
    for (int ks = 0; ks < 8; ++ks)
#pragma unroll
      for (int nt = 0; nt < 2; ++nt) {
        bf16x8 kf = *(const bf16x8*)&Ksh[p][((ks * 4 + quad) * 32 + nt * 16 + l16) * 8];
        s[0][nt] = MFMA16(aq[0][ks], kf, s[0][nt]);
        s[1][nt] = MFMA16(aq[1][ks], kf, s[1][nt]);
      }

    // mid barrier: V tile visible to both waves (waits only own V DMAs)
    __builtin_amdgcn_sched_barrier(0);
    __builtin_amdgcn_s_waitcnt(0x0F78);   // vmcnt(8): V done, K(it+1) in flight
    __builtin_amdgcn_s_barrier();
    __builtin_amdgcn_sched_barrier(0);

    // p = exp2(s*SCALE2 + SLOPE2*(col-row)) -> wave-private Psh
#pragma unroll
    for (int nt = 0; nt < 2; ++nt) {
      float ac = SLOPE2 * (float)(it * 32 + nt * 16 + l16);
#pragma unroll
      for (int mt = 0; mt < 2; ++mt)
#pragma unroll
        for (int r = 0; r < 4; ++r) {
          float a0 = ac - arb - SLOPE2 * (float)(mt * 16 + r);
          float pv = __builtin_amdgcn_exp2f(fmaf(s[mt][nt][r], SCALE2, a0));
          Psh[w][(mt * 16 + quad * 4 + r) * PSTR + nt * 16 + l16] = f2bf(pv);
        }
    }

    // PV + rowsum via ones-MFMA (compiler orders Psh write->read by lgkmcnt)
    bf16x8 pf0 = *(const bf16x8*)&Psh[w][l16 * PSTR + quad * 8];
    bf16x8 pf1 = *(const bf16x8*)&Psh[w][(16 + l16) * PSTR + quad * 8];
    lac[0] = MFMA16(pf0, vones, lac[0]);
    lac[1] = MFMA16(pf1, vones, lac[1]);
#pragma unroll
    for (int ht = 0; ht < 16; ++ht) {
      bf16x8 vf = *(const bf16x8*)&Vsh[(quad * 256 + ht * 16 + l16) * 8];
      O[0][ht] = MFMA16(pf0, vf, O[0][ht]);
      O[1][ht] = MFMA16(pf1, vf, O[1][ht]);
    }

    // end barrier: K(it+1) landed (issued a full iter ago) + V reads retired
    __builtin_amdgcn_sched_barrier(0);
    __builtin_amdgcn_s_waitcnt(0x0070);   // vmcnt(0) lgkm(0)
    __builtin_amdgcn_s_barrier();
    __builtin_amdgcn_sched_barrier(0);
  }

  float* ob = out + ((size_t)(b * T_) + q0 + w * 32) * H_;
#pragma unroll
  for (int mt = 0; mt < 2; ++mt)
#pragma unroll
    for (int r = 0; r < 4; ++r) {
      int row = mt * 16 + quad * 4 + r;
      float inv = 1.0f / lac[mt][r];
#pragma unroll
      for (int ht = 0; ht < 16; ++ht)
        ob[(size_t)row * H_ + ht * 16 + l16] = O[mt][ht][r] * inv;
    }
}

extern "C" void kernel_launch(void* const* d_in, const int* in_sizes, int n_in,
                              void* d_out, int out_size, void* d_ws, size_t ws_size,
                              hipStream_t stream) {
  const float* q = (const float*)d_in[0];
  const float* k = (const float*)d_in[1];
  const float* v = (const float*)d_in[2];
  float* out = (float*)d_out;

  const size_t elems = (size_t)B_ * T_ * H_;
  ushort* kt = (ushort*)d_ws;
  ushort* vt = kt + elems;

  prep_kernel<<<dim3(5120), 256, 0, stream>>>(k, v, kt, vt);
  attn_kernel<<<dim3(B_, T_ / 64), 128, 0, stream>>>(q, kt, vt, out);
}

// Round 8
// 165.129 us; speedup vs baseline: 2.2343x; 1.2495x over previous
//
#include <hip/hip_runtime.h>

#define B_ 8
#define T_ 2048
#define H_ 256
#define PSTR 40                  // P LDS row stride (elems)
#define SCALE2 0.0901684403f     // (1/16) * log2(e)
#define SLOPE2 0.00563552752f    // 2^-8 * log2(e)

typedef __attribute__((ext_vector_type(8))) short bf16x8;
typedef __attribute__((ext_vector_type(4))) float f32x4;

#define MFMA16(a, b, c) __builtin_amdgcn_mfma_f32_16x16x32_bf16((a), (b), (c), 0, 0, 0)

__device__ __forceinline__ ushort f2bf(float f) {
  unsigned u = __float_as_uint(f);
  u += 0x7FFFu + ((u >> 16) & 1u);   // RNE; finite inputs
  return (ushort)(u >> 16);
}

// async 16B/lane global->LDS DMA (contiguous: LDS = uniform base + lane*16)
__device__ __forceinline__ void gl_lds16(const ushort* g, ushort* l) {
  __builtin_amdgcn_global_load_lds(
      (const __attribute__((address_space(1))) unsigned int*)g,
      (__attribute__((address_space(3))) unsigned int*)l, 16, 0, 0);
}

// ---- prologue: blocks [0,4096) RoPE(k)->bf16 blocked ktile; [4096,5120) v transpose ----
// ktile layout: [b][it=t/32][d8=d/8][kv=t%32][8]   (16KB contiguous per (b,it) tile)
// vtile layout: [b][it][q4=(t%32)/8][h][8]
__global__ void prep_kernel(const float* __restrict__ k, const float* __restrict__ v,
                            ushort* __restrict__ kt, ushort* __restrict__ vt) {
  __shared__ ushort tile[64][72];
  const int bid = blockIdx.x;
  const int tid = threadIdx.x;
  if (bid < 4096) {
    int idx = bid * 256 + tid;          // over B*T*64 (j-pairs)
    int jp = idx & 63, bt = idx >> 6;
    int t = bt & (T_ - 1);
    int b = bt >> 11;
    int j = jp * 2;
    float rv0 = (float)t * exp2f((float)j * -0.103810252959f) * 0.15915494309f;
    float rv1 = (float)t * exp2f((float)(j + 1) * -0.103810252959f) * 0.15915494309f;
    float fr0 = rv0 - floorf(rv0), fr1 = rv1 - floorf(rv1);
    float sn0 = __builtin_amdgcn_sinf(fr0), cs0 = __builtin_amdgcn_cosf(fr0);
    float sn1 = __builtin_amdgcn_sinf(fr1), cs1 = __builtin_amdgcn_cosf(fr1);
    size_t base = (size_t)bt * H_ + j;
    float2 a = *(const float2*)(k + base);
    float2 c = *(const float2*)(k + base + 128);
    ushort2 lo, hi;
    lo.x = f2bf(a.x * cs0 - c.x * sn0); lo.y = f2bf(a.y * cs1 - c.y * sn1);
    hi.x = f2bf(c.x * cs0 + a.x * sn0); hi.y = f2bf(c.y * cs1 + a.y * sn1);
    size_t kdst = (((size_t)(b * 64 + (t >> 5)) * 32 + (j >> 3)) * 32 + (t & 31)) * 8 + (j & 7);
    *(ushort2*)(kt + kdst) = lo;
    *(ushort2*)(kt + kdst + 4096) = hi;   // d8 + 16
  } else {
    // V transpose into blocked vtile, 64x64 tiles, XOR-8 swizzle in LDS
    int bid2 = bid - 4096;
    int b = bid2 >> 7, rem = bid2 & 127;
    int h0 = (rem >> 5) * 64, t0 = (rem & 31) * 64;
    int c4 = tid & 15, r0 = tid >> 4;
#pragma unroll
    for (int p = 0; p < 4; ++p) {
      int row = r0 + p * 16;
      const float4 f = *(const float4*)(v + ((size_t)(b * T_ + t0 + row)) * H_ + h0 + c4 * 4);
      ushort4 u;
      u.x = f2bf(f.x); u.y = f2bf(f.y); u.z = f2bf(f.z); u.w = f2bf(f.w);
      *(ushort4*)&tile[row][(c4 * 4) ^ (8 * ((row >> 3) & 7))] = u;
    }
    __syncthreads();
#pragma unroll
    for (int p = 0; p < 2; ++p) {
      int c = tid + p * 256;
      int h = c >> 3, tc = (c & 7) * 8;
      int xo = 8 * (c & 7);
      ushort4 u0, u1;
      u0.x = tile[tc + 0][h ^ xo]; u0.y = tile[tc + 1][h ^ xo];
      u0.z = tile[tc + 2][h ^ xo]; u0.w = tile[tc + 3][h ^ xo];
      u1.x = tile[tc + 4][h ^ xo]; u1.y = tile[tc + 5][h ^ xo];
      u1.z = tile[tc + 6][h ^ xo]; u1.w = tile[tc + 7][h ^ xo];
      int tg = t0 + tc;
      size_t dst = (((size_t)(b * 64 + (tg >> 5)) * 4 + ((tg >> 3) & 3)) * 256 + (h0 + h)) * 8;
      *(ushort4*)(vt + dst) = u0;
      *(ushort4*)(vt + dst + 4) = u1;
    }
  }
}

// ---- Flash attention, kv-split x2: 512 blocks (2/CU), 2 waves x 32 rows each.
// K ping-pong + V single via global_load_lds; wave-private P; no-max softmax.
// Writes unnormalized O-partial + l-partial; combine kernel finishes.
__global__ __launch_bounds__(128, 1)
void attn_kernel(const float* __restrict__ q, const ushort* __restrict__ kt,
                 const ushort* __restrict__ vt, float* __restrict__ out,
                 float* __restrict__ o1, float* __restrict__ lpart) {
  __shared__ ushort Ksh[2][8192];       // [buf][d8][kv32][8]  32 KB
  __shared__ ushort Vsh[8192];          // [q4][h256][8]       16 KB
  __shared__ ushort Psh[2][32 * PSTR];  // per-wave P          5 KB

  const int tid = threadIdx.x;
  const int w = tid >> 6, lane = tid & 63, quad = lane >> 4, l16 = lane & 15;
  const int b = blockIdx.x;             // linear%8==b -> XCD affinity
  const int q0 = blockIdx.y * 64;
  const int sp = blockIdx.z;
  const int kvb = sp * (T_ / 2);        // global kv offset of this split

  // ---- in-register RoPE of this wave's 32 Q rows into A-frags ----
  bf16x8 aq[2][8];
  {
    const float* qb = q + ((size_t)(b * T_) + q0 + w * 32) * H_;
#pragma unroll
    for (int mt = 0; mt < 2; ++mt) {
      int t = q0 + w * 32 + mt * 16 + l16;
      float qv[8][8];
#pragma unroll
      for (int ks = 0; ks < 8; ++ks) {
        float4 x0 = *(const float4*)(qb + (size_t)(mt * 16 + l16) * H_ + ks * 32 + quad * 8);
        float4 x1 = *(const float4*)(qb + (size_t)(mt * 16 + l16) * H_ + ks * 32 + quad * 8 + 4);
        qv[ks][0] = x0.x; qv[ks][1] = x0.y; qv[ks][2] = x0.z; qv[ks][3] = x0.w;
        qv[ks][4] = x1.x; qv[ks][5] = x1.y; qv[ks][6] = x1.z; qv[ks][7] = x1.w;
      }
#pragma unroll
      for (int ks = 0; ks < 4; ++ks)
#pragma unroll
        for (int e = 0; e < 8; ++e) {
          int d = ks * 32 + quad * 8 + e;
          float rv = (float)t * exp2f((float)d * -0.103810252959f) * 0.15915494309f;
          float fr = rv - floorf(rv);
          float sn = __builtin_amdgcn_sinf(fr), cs = __builtin_amdgcn_cosf(fr);
          aq[mt][ks][e]     = (short)f2bf(qv[ks][e] * cs - qv[ks + 4][e] * sn);
          aq[mt][ks + 4][e] = (short)f2bf(qv[ks + 4][e] * cs + qv[ks][e] * sn);
        }
    }
  }

  const f32x4 fzero = {0.f, 0.f, 0.f, 0.f};
  f32x4 O[2][16], lac[2];
#pragma unroll
  for (int mt = 0; mt < 2; ++mt) {
    lac[mt] = fzero;
#pragma unroll
    for (int ht = 0; ht < 16; ++ht) O[mt][ht] = fzero;
  }
  bf16x8 vones;
#pragma unroll
  for (int i = 0; i < 8; ++i) vones[i] = (short)0x3F80;

  const ushort* ktb = kt + (size_t)(b * 64 + sp * 32) * 8192;
  const ushort* vtb = vt + (size_t)(b * 64 + sp * 32) * 8192;
  const int stoff = w * 4096 + lane * 8;   // elems: wave-half + lane*16B

  // preload K tile 0 into Ksh[0]
#pragma unroll
  for (int i = 0; i < 8; ++i)
    gl_lds16(ktb + stoff + i * 512, &Ksh[0][stoff + i * 512]);
  __builtin_amdgcn_sched_barrier(0);
  __builtin_amdgcn_s_waitcnt(0x0070);   // vmcnt(0) lgkm(0)
  __builtin_amdgcn_s_barrier();
  __builtin_amdgcn_sched_barrier(0);

  const float arb = SLOPE2 * (float)(q0 + w * 32 + quad * 4);

  for (int it = 0; it < 32; ++it) {
    const int p = it & 1;
    // issue V(it) then K(it+1) — V retires first (in-order vmcnt)
    {
      const ushort* vg = vtb + (size_t)it * 8192;
#pragma unroll
      for (int i = 0; i < 8; ++i)
        gl_lds16(vg + stoff + i * 512, &Vsh[stoff + i * 512]);
      const int itn = (it < 31) ? it + 1 : 31;
      const ushort* kg = ktb + (size_t)itn * 8192;
#pragma unroll
      for (int i = 0; i < 8; ++i)
        gl_lds16(kg + stoff + i * 512, &Ksh[1 - p][stoff + i * 512]);
    }
    __builtin_amdgcn_sched_barrier(0);

    // QK on Ksh[p]
    f32x4 s[2][2] = {{fzero, fzero}, {fzero, fzero}};
#pragma unroll
    for (int ks = 0; ks < 8; ++ks)
#pragma unroll
      for (int nt = 0; nt < 2; ++nt) {
        bf16x8 kf = *(const bf16x8*)&Ksh[p][((ks * 4 + quad) * 32 + nt * 16 + l16) * 8];
        s[0][nt] = MFMA16(aq[0][ks], kf, s[0][nt]);
        s[1][nt] = MFMA16(aq[1][ks], kf, s[1][nt]);
      }

    // mid barrier: V tile visible (waits only the V DMAs; K(it+1) stays in flight)
    __builtin_amdgcn_sched_barrier(0);
    __builtin_amdgcn_s_waitcnt(0x0F78);   // vmcnt(8)
    __builtin_amdgcn_s_barrier();
    __builtin_amdgcn_sched_barrier(0);

    // p = exp2(s*SCALE2 + SLOPE2*(col-row)) -> wave-private Psh
#pragma unroll
    for (int nt = 0; nt < 2; ++nt) {
      float ac = SLOPE2 * (float)(kvb + it * 32 + nt * 16 + l16);
#pragma unroll
      for (int mt = 0; mt < 2; ++mt)
#pragma unroll
        for (int r = 0; r < 4; ++r) {
          float a0 = ac - arb - SLOPE2 * (float)(mt * 16 + r);
          float pv = __builtin_amdgcn_exp2f(fmaf(s[mt][nt][r], SCALE2, a0));
          Psh[w][(mt * 16 + quad * 4 + r) * PSTR + nt * 16 + l16] = f2bf(pv);
        }
    }

    // PV + rowsum via ones-MFMA (lgkmcnt orders the wave-private write->read)
    bf16x8 pf0 = *(const bf16x8*)&Psh[w][l16 * PSTR + quad * 8];
    bf16x8 pf1 = *(const bf16x8*)&Psh[w][(16 + l16) * PSTR + quad * 8];
    lac[0] = MFMA16(pf0, vones, lac[0]);
    lac[1] = MFMA16(pf1, vones, lac[1]);
#pragma unroll
    for (int ht = 0; ht < 16; ++ht) {
      bf16x8 vf = *(const bf16x8*)&Vsh[(quad * 256 + ht * 16 + l16) * 8];
      O[0][ht] = MFMA16(pf0, vf, O[0][ht]);
      O[1][ht] = MFMA16(pf1, vf, O[1][ht]);
    }

    // end barrier: K(it+1) landed (issued a full iter ago), LDS reads retired
    __builtin_amdgcn_sched_barrier(0);
    __builtin_amdgcn_s_waitcnt(0x0070);   // vmcnt(0) lgkm(0)
    __builtin_amdgcn_s_barrier();
    __builtin_amdgcn_sched_barrier(0);
  }

  // epilogue: unnormalized O-partial + l-partial
  float* od = (sp == 0) ? out : o1;
  float* ob = od + ((size_t)(b * T_) + q0 + w * 32) * H_;
#pragma unroll
  for (int mt = 0; mt < 2; ++mt)
#pragma unroll
    for (int r = 0; r < 4; ++r) {
      int row = mt * 16 + quad * 4 + r;
#pragma unroll
      for (int ht = 0; ht < 16; ++ht)
        ob[(size_t)row * H_ + ht * 16 + l16] = O[mt][ht][r];
    }
  if (l16 == 0) {
#pragma unroll
    for (int mt = 0; mt < 2; ++mt)
#pragma unroll
      for (int r = 0; r < 4; ++r)
        lpart[(size_t)(sp * B_ + b) * T_ + q0 + w * 32 + mt * 16 + quad * 4 + r] =
            lac[mt][r];
  }
}

// ---- combine: out = (O0 + O1) / (l0 + l1) ----
__global__ void combine_kernel(float* __restrict__ out, const float* __restrict__ o1,
                               const float* __restrict__ lpart) {
  int idx = blockIdx.x * 256 + threadIdx.x;   // over B*T*H/4
  int row = idx >> 6;
  float inv = 1.0f / (lpart[row] + lpart[B_ * T_ + row]);
  float4 a = ((const float4*)out)[idx];
  float4 c = ((const float4*)o1)[idx];
  a.x = (a.x + c.x) * inv; a.y = (a.y + c.y) * inv;
  a.z = (a.z + c.z) * inv; a.w = (a.w + c.w) * inv;
  ((float4*)out)[idx] = a;
}

extern "C" void kernel_launch(void* const* d_in, const int* in_sizes, int n_in,
                              void* d_out, int out_size, void* d_ws, size_t ws_size,
                              hipStream_t stream) {
  const float* q = (const float*)d_in[0];
  const float* k = (const float*)d_in[1];
  const float* v = (const float*)d_in[2];
  float* out = (float*)d_out;

  const size_t elems = (size_t)B_ * T_ * H_;
  ushort* kt = (ushort*)d_ws;
  ushort* vt = kt + elems;
  float* o1 = (float*)(vt + elems);
  float* lpart = o1 + elems;            // 2*B*T floats

  prep_kernel<<<dim3(5120), 256, 0, stream>>>(k, v, kt, vt);
  attn_kernel<<<dim3(B_, T_ / 64, 2), 128, 0, stream>>>(q, kt, vt, out, o1, lpart);
  combine_kernel<<<dim3((B_ * T_ * H_ / 4) / 256), 256, 0, stream>>>(out, o1, lpart);
}